// Round 5
// baseline (1003.456 us; speedup 1.0000x reference)
//
#include <hip/hip_runtime.h>
#include <hip/hip_bf16.h>
#include <cstdint>

#define BB 64
#define TT 2048
#define FD 256
#define UU 32
#define NC 4            // batch-chains interleaved per wave in vit_values

// ---------------------------------------------------------------------------
// Kernel 1: pot[b,t,u] = dot(x[b,t,:], K[:,u]) + bias[u] (+ boundaries)
// (unchanged, verified)
// ---------------------------------------------------------------------------
__global__ __launch_bounds__(64) void potentials_kernel(
    const float* __restrict__ x, const float* __restrict__ K,
    const float* __restrict__ bias, const float* __restrict__ lb,
    const float* __restrict__ rb, float* __restrict__ pot)
{
    __shared__ __align__(16) float lds[16384];   // 64 KB total
    float* xs = lds;            // [32 rows][256 f], swizzled quads
    float* Kt = lds + 8192;     // [32 u]  [256 f], swizzled quads

    const int tid = threadIdx.x;
    const int ug = tid & 7;
    const int rg = tid >> 3;

    for (int j = 0; j < 128; ++j) {
        const int e = j * 64 + tid;
        const int f = e >> 5;
        const int u = e & 31;
        Kt[u * 256 + (((f >> 2) ^ (u & 7)) << 2) + (f & 3)] = K[e];
    }

    float bu[4], lu4[4], ru4[4];
    #pragma unroll
    for (int m = 0; m < 4; ++m) {
        bu[m]  = bias[ug + 8 * m];
        lu4[m] = lb[ug + 8 * m];
        ru4[m] = rb[ug + 8 * m];
    }

    const int tiles = (BB * TT) / 32;     // 4096
    for (int tile = blockIdx.x; tile < tiles; tile += gridDim.x) {
        const int row0 = tile * 32;
        __syncthreads();
        #pragma unroll 4
        for (int k = 0; k < 32; ++k) {
            const float4 v = *(const float4*)(x + (size_t)(row0 + k) * FD + tid * 4);
            *(float4*)&xs[k * 256 + ((tid ^ (k & 7)) << 2)] = v;
        }
        __syncthreads();

        float acc[4][4];
        #pragma unroll
        for (int i = 0; i < 4; ++i)
            #pragma unroll
            for (int m = 0; m < 4; ++m) acc[i][m] = 0.f;

        #pragma unroll 4
        for (int q = 0; q < 64; ++q) {
            float4 xq[4], kq[4];
            #pragma unroll
            for (int i = 0; i < 4; ++i)
                xq[i] = *(const float4*)&xs[(rg + 8 * i) * 256 + ((q ^ rg) << 2)];
            #pragma unroll
            for (int m = 0; m < 4; ++m)
                kq[m] = *(const float4*)&Kt[(ug + 8 * m) * 256 + ((q ^ ug) << 2)];
            #pragma unroll
            for (int i = 0; i < 4; ++i)
                #pragma unroll
                for (int m = 0; m < 4; ++m) {
                    acc[i][m] += xq[i].x * kq[m].x;
                    acc[i][m] += xq[i].y * kq[m].y;
                    acc[i][m] += xq[i].z * kq[m].z;
                    acc[i][m] += xq[i].w * kq[m].w;
                }
        }

        #pragma unroll
        for (int i = 0; i < 4; ++i) {
            const int row = row0 + rg + 8 * i;
            const int t = row & (TT - 1);
            #pragma unroll
            for (int m = 0; m < 4; ++m) {
                pot[(size_t)row * UU + ug + 8 * m] =
                    acc[i][m] + bu[m] + (t == 0 ? lu4[m] : 0.f)
                              + (t == TT - 1 ? ru4[m] : 0.f);
            }
        }
    }
}

// ---------------------------------------------------------------------------
// quad_perm [1,0,3,2]: swap adjacent lane pairs via DPP (VALU pipe, verified).
// ---------------------------------------------------------------------------
__device__ __forceinline__ float quad_swap(float v) {
    const int i = __float_as_int(v);
    const int r = __builtin_amdgcn_update_dpp(i, i, 0xB1, 0xF, 0xF, true);
    return __int_as_float(r);
}

// ---------------------------------------------------------------------------
// Kernel 2: values-only serial forward, v5 — chain interleaving.
// r4 lesson: with ONE wave/CU the step executes at dependent-latency rate
// (~230 cyc) regardless of broadcast primitive (LDS roundtrip ~= DPP
// butterfly + hazard waits); there is no TLP to hide anything. Fix: pack
// NC=4 independent batch-chains into each wave (grid 16) and interleave
// their steps. Each chain's LDS-broadcast latency (~190 cyc) hides under
// the other 3 chains' ~200 cyc of independent VALU work -> issue-bound
// (~33 VALU inst/step -> ~70-90 cyc/step/chain).
// Per-chain arithmetic is byte-for-byte the verified v1 step (same rounded
// adds, same max tree, same quad_swap merge, single-rounded +pot), so chk
// is bit-identical and the window/backtrack kernels stay consistent.
// All chain indices are compile-time (no runtime-indexed register arrays).
// ---------------------------------------------------------------------------
__global__ __launch_bounds__(64) void vit_values_kernel(
    const float* __restrict__ pot, const float* __restrict__ chain,
    float* __restrict__ chk)
{
    __shared__ __align__(16) float mb[NC][32];

    const int lane = threadIdx.x;
    const int u = lane >> 1;
    const int q = lane & 1;
    const int qb = 16 * q;
    const int b0 = blockIdx.x * NC;

    const float* pb0 = pot + (size_t)(b0 + 0) * TT * UU;
    const float* pb1 = pot + (size_t)(b0 + 1) * TT * UU;
    const float* pb2 = pot + (size_t)(b0 + 2) * TT * UU;
    const float* pb3 = pot + (size_t)(b0 + 3) * TT * UU;

    // chain matrix is shared by all chains: cc[i] = chain[qb+i][u]
    float cc[16];
    #pragma unroll
    for (int i = 0; i < 16; ++i) cc[i] = chain[(qb + i) * UU + u];

    float s0[16], s1[16], s2[16], s3[16];
    {
        const float4* a0 = (const float4*)(pb0 + qb);
        const float4* a1 = (const float4*)(pb1 + qb);
        const float4* a2 = (const float4*)(pb2 + qb);
        const float4* a3 = (const float4*)(pb3 + qb);
        #pragma unroll
        for (int k = 0; k < 4; ++k) {
            const float4 v0 = a0[k], v1 = a1[k], v2 = a2[k], v3 = a3[k];
            s0[4*k+0]=v0.x; s0[4*k+1]=v0.y; s0[4*k+2]=v0.z; s0[4*k+3]=v0.w;
            s1[4*k+0]=v1.x; s1[4*k+1]=v1.y; s1[4*k+2]=v1.z; s1[4*k+3]=v1.w;
            s2[4*k+0]=v2.x; s2[4*k+1]=v2.y; s2[4*k+2]=v2.z; s2[4*k+3]=v2.w;
            s3[4*k+0]=v3.x; s3[4*k+1]=v3.y; s3[4*k+2]=v3.z; s3[4*k+3]=v3.w;
        }
    }

    // One step of one chain. sc/mbc identify the chain (constant at each
    // call site); arithmetic identical to verified v1.
    auto step = [&](float (&sc)[16], float* mbc, float potv, int t, int bb) {
        float a[16];
        #pragma unroll
        for (int i = 0; i < 16; ++i) a[i] = sc[i] + cc[i];
        float m8[8];
        #pragma unroll
        for (int i = 0; i < 8; ++i) m8[i] = fmaxf(a[2*i], a[2*i+1]);
        float m4[4];
        #pragma unroll
        for (int i = 0; i < 4; ++i) m4[i] = fmaxf(m8[2*i], m8[2*i+1]);
        const float pm = fmaxf(fmaxf(m4[0], m4[1]), fmaxf(m4[2], m4[3]));
        const float om = quad_swap(pm);          // other half's partial max
        const float mm = fmaxf(pm, om) + potv;   // exact max, single rounding

        if ((t & 63) == 63)
            chk[((size_t)bb * 33 + ((t >> 6) + 1)) * UU + u] = mm;

        mbc[u] = mm;                             // both q-lanes, same value
        const float4 x0 = *(const float4*)&mbc[qb + 0];
        const float4 x1 = *(const float4*)&mbc[qb + 4];
        const float4 x2 = *(const float4*)&mbc[qb + 8];
        const float4 x3 = *(const float4*)&mbc[qb + 12];
        sc[0]=x0.x;  sc[1]=x0.y;  sc[2]=x0.z;  sc[3]=x0.w;
        sc[4]=x1.x;  sc[5]=x1.y;  sc[6]=x1.z;  sc[7]=x1.w;
        sc[8]=x2.x;  sc[9]=x2.y;  sc[10]=x2.z; sc[11]=x2.w;
        sc[12]=x3.x; sc[13]=x3.y; sc[14]=x3.z; sc[15]=x3.w;
    };

    // pot-value prefetch, group of 4 steps
    float pr0[4], pr1[4], pr2[4], pr3[4];
    float pn0[4], pn1[4], pn2[4], pn3[4];
    #pragma unroll
    for (int j = 0; j < 4; ++j) {
        pr0[j] = pb0[(1 + j) * UU + u];
        pr1[j] = pb1[(1 + j) * UU + u];
        pr2[j] = pb2[(1 + j) * UU + u];
        pr3[j] = pb3[(1 + j) * UU + u];
    }

    #pragma unroll 1
    for (int g = 0; g < 511; ++g) {
        const int t0 = 1 + 4 * g;
        #pragma unroll
        for (int j = 0; j < 4; ++j) {
            int tp = t0 + 4 + j;
            if (tp > TT - 1) tp = TT - 1;
            pn0[j] = pb0[tp * UU + u];
            pn1[j] = pb1[tp * UU + u];
            pn2[j] = pb2[tp * UU + u];
            pn3[j] = pb3[tp * UU + u];
        }
        #pragma unroll
        for (int j = 0; j < 4; ++j) {
            step(s0, &mb[0][0], pr0[j], t0 + j, b0 + 0);
            step(s1, &mb[1][0], pr1[j], t0 + j, b0 + 1);
            step(s2, &mb[2][0], pr2[j], t0 + j, b0 + 2);
            step(s3, &mb[3][0], pr3[j], t0 + j, b0 + 3);
        }
        #pragma unroll
        for (int j = 0; j < 4; ++j) {
            pr0[j] = pn0[j]; pr1[j] = pn1[j];
            pr2[j] = pn2[j]; pr3[j] = pn3[j];
        }
    }
    // groups covered t = 1..2044; tail t = 2045..2047 (pr holds them,
    // loaded with clamp; includes final checkpoint wck=32 at t=2047)
    #pragma unroll
    for (int j = 0; j < 3; ++j) {
        step(s0, &mb[0][0], pr0[j], 2045 + j, b0 + 0);
        step(s1, &mb[1][0], pr1[j], 2045 + j, b0 + 1);
        step(s2, &mb[2][0], pr2[j], 2045 + j, b0 + 2);
        step(s3, &mb[3][0], pr3[j], 2045 + j, b0 + 3);
    }
}

// ---------------------------------------------------------------------------
// Kernel 3: parallel window recompute (unchanged, verified).
// ---------------------------------------------------------------------------
__global__ __launch_bounds__(64) void vit_window_kernel(
    const float* __restrict__ pot, const float* __restrict__ chain,
    const float* __restrict__ chk, unsigned char* __restrict__ Mg,
    unsigned char* __restrict__ bpg)
{
    __shared__ float potL[64 * 32];   // 8 KB: pot rows 64w .. 64w+63
    __shared__ float mbuf[32];

    const int lane = threadIdx.x;
    const int u = lane & 31;
    const int h = lane >> 5;
    const int hbase = 16 * h;
    const int w = blockIdx.x;
    const int b = blockIdx.y;
    const float* pb = pot + (size_t)b * TT * UU;
    const int r0 = 64 * w;

    {
        const float4* src = (const float4*)(pb + (size_t)r0 * UU);
        float4* dst = (float4*)potL;
        #pragma unroll
        for (int k = 0; k < 8; ++k) dst[lane + 64 * k] = src[lane + 64 * k];
    }
    __syncthreads();

    float cc[16];
    #pragma unroll
    for (int i = 0; i < 16; ++i) cc[i] = chain[(hbase + i) * UU + u];

    float s[16];
    if (w == 0) {
        #pragma unroll
        for (int i = 0; i < 16; ++i) s[i] = potL[hbase + i];          // state t=0
    } else {
        #pragma unroll
        for (int i = 0; i < 16; ++i) s[i] = chk[((size_t)b * 33 + w) * UU + hbase + i];
    }

    int orig = u;
    unsigned char* bb = bpg + (size_t)b * (TT - 1) * UU;

    const int tl0 = (w == 0) ? 1 : 0;
    #pragma unroll 1
    for (int tl = tl0; tl < 64; ++tl) {
        const int t = r0 + tl;
        const float potv = potL[tl * UU + u];

        float a[16];
        #pragma unroll
        for (int i = 0; i < 16; ++i) a[i] = s[i] + cc[i];

        // first-occurrence argmax: pairwise tree, right wins only if strictly >
        float v8[8]; int i8[8];
        #pragma unroll
        for (int i = 0; i < 8; ++i) {
            const bool c = a[2*i+1] > a[2*i];
            v8[i] = c ? a[2*i+1] : a[2*i];
            i8[i] = c ? (2*i+1) : (2*i);
        }
        float v4[4]; int i4[4];
        #pragma unroll
        for (int i = 0; i < 4; ++i) {
            const bool c = v8[2*i+1] > v8[2*i];
            v4[i] = c ? v8[2*i+1] : v8[2*i];
            i4[i] = c ? i8[2*i+1] : i8[2*i];
        }
        float v2[2]; int i2[2];
        #pragma unroll
        for (int i = 0; i < 2; ++i) {
            const bool c = v4[2*i+1] > v4[2*i];
            v2[i] = c ? v4[2*i+1] : v4[2*i];
            i2[i] = c ? i4[2*i+1] : i4[2*i];
        }
        const bool cf = v2[1] > v2[0];
        const float pv = cf ? v2[1] : v2[0];
        const int pidx = hbase + (cf ? i2[1] : i2[0]);

        const float opv = __shfl_xor(pv, 32, 64);
        const int   opi = __shfl_xor(pidx, 32, 64);
        const bool take = h ? (opv >= pv) : (opv > pv);   // tie -> lower half
        const int  mv   = take ? opi : pidx;
        const float mm  = fmaxf(pv, opv) + potv;

        if (h == 0) bb[(size_t)(t - 1) * UU + u] = (unsigned char)mv;
        orig = __shfl(orig, mv, 64);

        mbuf[u] = mm;
        const float4 x0 = *(const float4*)&mbuf[hbase + 0];
        const float4 x1 = *(const float4*)&mbuf[hbase + 4];
        const float4 x2 = *(const float4*)&mbuf[hbase + 8];
        const float4 x3 = *(const float4*)&mbuf[hbase + 12];
        s[0]=x0.x; s[1]=x0.y; s[2]=x0.z;  s[3]=x0.w;
        s[4]=x1.x; s[5]=x1.y; s[6]=x1.z;  s[7]=x1.w;
        s[8]=x2.x; s[9]=x2.y; s[10]=x2.z; s[11]=x2.w;
        s[12]=x3.x; s[13]=x3.y; s[14]=x3.z; s[15]=x3.w;
    }

    if (h == 0) Mg[(size_t)b * 1024 + w * UU + u] = (unsigned char)orig;
}

// ---------------------------------------------------------------------------
// Kernel 4: per-batch backtrack (unchanged, verified).
// ---------------------------------------------------------------------------
__global__ __launch_bounds__(64) void vit_backtrack_kernel(
    const float* __restrict__ chk, const unsigned char* __restrict__ Mg,
    const unsigned char* __restrict__ bpg, int* __restrict__ out)
{
    __shared__ __align__(16) unsigned char bp[(TT - 1) * UU];   // 65504 B

    const int lane = threadIdx.x;
    const int b = blockIdx.x;
    const unsigned char* bb = bpg + (size_t)b * (TT - 1) * UU;

    // stage bp: 4094 int4s
    #pragma unroll 4
    for (int i = 0; i < 64; ++i) {
        const int idx = i * 64 + lane;
        if (idx < 4094)
            ((int4*)bp)[idx] = ((const int4*)bb)[idx];
    }

    // last_tag = argmax_u chk[b][32][u], smallest u on tie
    float fv = (lane < 32) ? chk[((size_t)b * 33 + 32) * UU + lane] : -INFINITY;
    int fi = lane & 31;
    #pragma unroll
    for (int mask = 16; mask >= 1; mask >>= 1) {
        const float ov = __shfl_xor(fv, mask, 64);
        const int oi = __shfl_xor(fi, mask, 64);
        if (ov > fv || (ov == fv && oi < fi)) { fv = ov; fi = oi; }
    }
    int bt = __shfl(fi, 0, 64);

    // boundary walk over Mg (uniform addresses -> broadcast global loads)
    int my_btag = 0;
    #pragma unroll 1
    for (int w = 31; w >= 0; --w) {
        if (lane == w) my_btag = bt;         // tag at t = 64w+63
        bt = Mg[(size_t)b * 1024 + w * 32 + bt];
    }

    __syncthreads();                         // bp staging visible

    if (lane < 32) {
        const int w = lane;
        int tag = my_btag;
        int t = w * 64 + 63;
        int* ob = out + (size_t)b * TT;
        ob[t] = tag;
        #pragma unroll 1
        for (; t >= w * 64 + 1; --t) {
            tag = bp[(t - 1) * UU + tag];
            ob[t - 1] = tag;
        }
    }
}

// ---------------------------------------------------------------------------
extern "C" void kernel_launch(void* const* d_in, const int* in_sizes, int n_in,
                              void* d_out, int out_size, void* d_ws, size_t ws_size,
                              hipStream_t stream)
{
    const float* x     = (const float*)d_in[0];
    const float* K     = (const float*)d_in[1];
    const float* bias  = (const float*)d_in[2];
    const float* chain = (const float*)d_in[3];
    const float* lb    = (const float*)d_in[4];
    const float* rb    = (const float*)d_in[5];
    int* out = (int*)d_out;

    float* pot = (float*)d_ws;                          // 16 MB
    float* chk = pot + (size_t)BB * TT * UU;            // 64*33*32 floats = 264 KB
    unsigned char* Mg  = (unsigned char*)(chk + (size_t)BB * 33 * UU);  // 64 KB
    unsigned char* bpg = Mg + (size_t)BB * 32 * UU;     // 64*2047*32 = 4 MB

    potentials_kernel<<<512, 64, 0, stream>>>(x, K, bias, lb, rb, pot);
    vit_values_kernel<<<BB / NC, 64, 0, stream>>>(pot, chain, chk);
    vit_window_kernel<<<dim3(32, BB), 64, 0, stream>>>(pot, chain, chk, Mg, bpg);
    vit_backtrack_kernel<<<BB, 64, 0, stream>>>(chk, Mg, bpg, out);
}

// Round 6
// 629.478 us; speedup vs baseline: 1.5941x; 1.5941x over previous
//
#include <hip/hip_runtime.h>
#include <hip/hip_bf16.h>
#include <cstdint>

#define BB 64
#define TT 2048
#define FD 256
#define UU 32

// ---------------------------------------------------------------------------
// Kernel 1: pot[b,t,u] = dot(x[b,t,:], K[:,u]) + bias[u] (+ boundaries)
// One wave per block. Both operands in LDS, XOR-swizzled quad layout:
// element quad q of row r lives at slot (q ^ (r&7)) -> every ds_read_b128 is
// conflict-free (8 distinct bank-groups x 8-way same-address broadcast).
// Thread (ug=tid&7, rg=tid>>3) computes rows {rg+8i} x cols {ug+8m}, i,m<4:
// 2 B of LDS per FMA. Ascending-f sequential accumulation (bit-identical pot).
// NOTE (round 6): launched TWICE this round as a timing probe — idempotent
// (pure function of inputs), so the total-duration delta == this kernel's
// per-dispatch time, which top-5 profiling cannot otherwise reveal.
// ---------------------------------------------------------------------------
__global__ __launch_bounds__(64) void potentials_kernel(
    const float* __restrict__ x, const float* __restrict__ K,
    const float* __restrict__ bias, const float* __restrict__ lb,
    const float* __restrict__ rb, float* __restrict__ pot)
{
    __shared__ __align__(16) float lds[16384];   // 64 KB total
    float* xs = lds;            // [32 rows][256 f], swizzled quads
    float* Kt = lds + 8192;     // [32 u]  [256 f], swizzled quads

    const int tid = threadIdx.x;
    const int ug = tid & 7;
    const int rg = tid >> 3;

    // Stage K (once): K is [f][u] row-major -> Kt[u][f] swizzled.
    for (int j = 0; j < 128; ++j) {
        const int e = j * 64 + tid;
        const int f = e >> 5;
        const int u = e & 31;
        Kt[u * 256 + (((f >> 2) ^ (u & 7)) << 2) + (f & 3)] = K[e];
    }

    float bu[4], lu4[4], ru4[4];
    #pragma unroll
    for (int m = 0; m < 4; ++m) {
        bu[m]  = bias[ug + 8 * m];
        lu4[m] = lb[ug + 8 * m];
        ru4[m] = rb[ug + 8 * m];
    }

    const int tiles = (BB * TT) / 32;     // 4096
    for (int tile = blockIdx.x; tile < tiles; tile += gridDim.x) {
        const int row0 = tile * 32;
        __syncthreads();                  // protect xs from previous readers
        #pragma unroll 4
        for (int k = 0; k < 32; ++k) {
            const float4 v = *(const float4*)(x + (size_t)(row0 + k) * FD + tid * 4);
            *(float4*)&xs[k * 256 + ((tid ^ (k & 7)) << 2)] = v;
        }
        __syncthreads();

        float acc[4][4];
        #pragma unroll
        for (int i = 0; i < 4; ++i)
            #pragma unroll
            for (int m = 0; m < 4; ++m) acc[i][m] = 0.f;

        #pragma unroll 4
        for (int q = 0; q < 64; ++q) {
            float4 xq[4], kq[4];
            #pragma unroll
            for (int i = 0; i < 4; ++i)
                xq[i] = *(const float4*)&xs[(rg + 8 * i) * 256 + ((q ^ rg) << 2)];
            #pragma unroll
            for (int m = 0; m < 4; ++m)
                kq[m] = *(const float4*)&Kt[(ug + 8 * m) * 256 + ((q ^ ug) << 2)];
            #pragma unroll
            for (int i = 0; i < 4; ++i)
                #pragma unroll
                for (int m = 0; m < 4; ++m) {
                    acc[i][m] += xq[i].x * kq[m].x;
                    acc[i][m] += xq[i].y * kq[m].y;
                    acc[i][m] += xq[i].z * kq[m].z;
                    acc[i][m] += xq[i].w * kq[m].w;
                }
        }

        #pragma unroll
        for (int i = 0; i < 4; ++i) {
            const int row = row0 + rg + 8 * i;
            const int t = row & (TT - 1);
            #pragma unroll
            for (int m = 0; m < 4; ++m) {
                pot[(size_t)row * UU + ug + 8 * m] =
                    acc[i][m] + bu[m] + (t == 0 ? lu4[m] : 0.f)
                              + (t == TT - 1 ? ru4[m] : 0.f);
            }
        }
    }
}

// ---------------------------------------------------------------------------
// quad_perm [1,0,3,2]: swap adjacent lane pairs via DPP (VALU pipe, no LDS).
// ---------------------------------------------------------------------------
__device__ __forceinline__ float quad_swap(float v) {
    const int i = __float_as_int(v);
    const int r = __builtin_amdgcn_update_dpp(i, i, 0xB1, 0xF, 0xF, true);
    return __int_as_float(r);
}

// ---------------------------------------------------------------------------
// Kernel 2: values-only serial forward — EXACT round-0 v1 restore (195.8 us
// verified). One chain per wave; wall time = per-chain serial latency.
// Rounds 1-5 lesson: LDS roundtrip (~190cy) ~= DPP butterfly (~200cy) per
// step; NC-packing chains into one wave only serializes (671 us). The v1
// structure is the best known for this latency chain.
// ---------------------------------------------------------------------------
__global__ __launch_bounds__(64) void vit_values_kernel(
    const float* __restrict__ pot, const float* __restrict__ chain,
    float* __restrict__ chk)
{
    __shared__ __align__(16) float mbuf[32];

    const int lane = threadIdx.x;
    const int u = lane >> 1;
    const int q = lane & 1;
    const int qb = 16 * q;
    const int b = blockIdx.x;
    const float* pb = pot + (size_t)b * TT * UU;

    float cc[16];
    #pragma unroll
    for (int i = 0; i < 16; ++i) cc[i] = chain[(qb + i) * UU + u];

    float s[16];
    {
        const float4* s0 = (const float4*)(pb + qb);
        #pragma unroll
        for (int k = 0; k < 4; ++k) {
            const float4 v = s0[k];
            s[4*k+0] = v.x; s[4*k+1] = v.y; s[4*k+2] = v.z; s[4*k+3] = v.w;
        }
    }

    auto step = [&](float potv, int t) {
        float a[16];
        #pragma unroll
        for (int i = 0; i < 16; ++i) a[i] = s[i] + cc[i];
        float m8[8];
        #pragma unroll
        for (int i = 0; i < 8; ++i) m8[i] = fmaxf(a[2*i], a[2*i+1]);
        float m4[4];
        #pragma unroll
        for (int i = 0; i < 4; ++i) m4[i] = fmaxf(m8[2*i], m8[2*i+1]);
        const float pm = fmaxf(fmaxf(m4[0], m4[1]), fmaxf(m4[2], m4[3]));
        const float om = quad_swap(pm);          // other half's partial max
        const float mm = fmaxf(pm, om) + potv;   // exact max, single rounding

        mbuf[u] = mm;                            // both q-lanes write same value

        if ((t & 63) == 63)
            chk[((size_t)b * 33 + ((t >> 6) + 1)) * UU + u] = mm;

        const float4 x0 = *(const float4*)&mbuf[qb + 0];
        const float4 x1 = *(const float4*)&mbuf[qb + 4];
        const float4 x2 = *(const float4*)&mbuf[qb + 8];
        const float4 x3 = *(const float4*)&mbuf[qb + 12];
        s[0]=x0.x;  s[1]=x0.y;  s[2]=x0.z;  s[3]=x0.w;
        s[4]=x1.x;  s[5]=x1.y;  s[6]=x1.z;  s[7]=x1.w;
        s[8]=x2.x;  s[9]=x2.y;  s[10]=x2.z; s[11]=x2.w;
        s[12]=x3.x; s[13]=x3.y; s[14]=x3.z; s[15]=x3.w;
    };

    float pr[8], pn[8];
    #pragma unroll
    for (int j = 0; j < 8; ++j) pr[j] = pb[(1 + j) * UU + u];

    #pragma unroll 1
    for (int g = 0; g < 255; ++g) {
        #pragma unroll
        for (int j = 0; j < 8; ++j) {
            int tp = 9 + 8 * g + j;
            if (tp > TT - 1) tp = TT - 1;
            pn[j] = pb[tp * UU + u];
        }
        const int t0 = 1 + 8 * g;
        #pragma unroll
        for (int j = 0; j < 8; ++j)
            step(pr[j], t0 + j);
        #pragma unroll
        for (int j = 0; j < 8; ++j) pr[j] = pn[j];
    }
    // tail: t = 2041..2047 (includes final checkpoint wck = 32 at t = 2047)
    #pragma unroll
    for (int j = 0; j < 7; ++j)
        step(pr[j], 2041 + j);
}

// ---------------------------------------------------------------------------
// Kernel 3: parallel window recompute (unchanged, verified).
// ---------------------------------------------------------------------------
__global__ __launch_bounds__(64) void vit_window_kernel(
    const float* __restrict__ pot, const float* __restrict__ chain,
    const float* __restrict__ chk, unsigned char* __restrict__ Mg,
    unsigned char* __restrict__ bpg)
{
    __shared__ float potL[64 * 32];   // 8 KB: pot rows 64w .. 64w+63
    __shared__ float mbuf[32];

    const int lane = threadIdx.x;
    const int u = lane & 31;
    const int h = lane >> 5;
    const int hbase = 16 * h;
    const int w = blockIdx.x;
    const int b = blockIdx.y;
    const float* pb = pot + (size_t)b * TT * UU;
    const int r0 = 64 * w;

    {
        const float4* src = (const float4*)(pb + (size_t)r0 * UU);
        float4* dst = (float4*)potL;
        #pragma unroll
        for (int k = 0; k < 8; ++k) dst[lane + 64 * k] = src[lane + 64 * k];
    }
    __syncthreads();

    float cc[16];
    #pragma unroll
    for (int i = 0; i < 16; ++i) cc[i] = chain[(hbase + i) * UU + u];

    float s[16];
    if (w == 0) {
        #pragma unroll
        for (int i = 0; i < 16; ++i) s[i] = potL[hbase + i];          // state t=0
    } else {
        #pragma unroll
        for (int i = 0; i < 16; ++i) s[i] = chk[((size_t)b * 33 + w) * UU + hbase + i];
    }

    int orig = u;
    unsigned char* bb = bpg + (size_t)b * (TT - 1) * UU;

    const int tl0 = (w == 0) ? 1 : 0;
    #pragma unroll 1
    for (int tl = tl0; tl < 64; ++tl) {
        const int t = r0 + tl;
        const float potv = potL[tl * UU + u];

        float a[16];
        #pragma unroll
        for (int i = 0; i < 16; ++i) a[i] = s[i] + cc[i];

        // first-occurrence argmax: pairwise tree, right wins only if strictly >
        float v8[8]; int i8[8];
        #pragma unroll
        for (int i = 0; i < 8; ++i) {
            const bool c = a[2*i+1] > a[2*i];
            v8[i] = c ? a[2*i+1] : a[2*i];
            i8[i] = c ? (2*i+1) : (2*i);
        }
        float v4[4]; int i4[4];
        #pragma unroll
        for (int i = 0; i < 4; ++i) {
            const bool c = v8[2*i+1] > v8[2*i];
            v4[i] = c ? v8[2*i+1] : v8[2*i];
            i4[i] = c ? i8[2*i+1] : i8[2*i];
        }
        float v2[2]; int i2[2];
        #pragma unroll
        for (int i = 0; i < 2; ++i) {
            const bool c = v4[2*i+1] > v4[2*i];
            v2[i] = c ? v4[2*i+1] : v4[2*i];
            i2[i] = c ? i4[2*i+1] : i4[2*i];
        }
        const bool cf = v2[1] > v2[0];
        const float pv = cf ? v2[1] : v2[0];
        const int pidx = hbase + (cf ? i2[1] : i2[0]);

        const float opv = __shfl_xor(pv, 32, 64);
        const int   opi = __shfl_xor(pidx, 32, 64);
        const bool take = h ? (opv >= pv) : (opv > pv);   // tie -> lower half
        const int  mv   = take ? opi : pidx;
        const float mm  = fmaxf(pv, opv) + potv;

        if (h == 0) bb[(size_t)(t - 1) * UU + u] = (unsigned char)mv;
        orig = __shfl(orig, mv, 64);

        mbuf[u] = mm;
        const float4 x0 = *(const float4*)&mbuf[hbase + 0];
        const float4 x1 = *(const float4*)&mbuf[hbase + 4];
        const float4 x2 = *(const float4*)&mbuf[hbase + 8];
        const float4 x3 = *(const float4*)&mbuf[hbase + 12];
        s[0]=x0.x; s[1]=x0.y; s[2]=x0.z;  s[3]=x0.w;
        s[4]=x1.x; s[5]=x1.y; s[6]=x1.z;  s[7]=x1.w;
        s[8]=x2.x; s[9]=x2.y; s[10]=x2.z; s[11]=x2.w;
        s[12]=x3.x; s[13]=x3.y; s[14]=x3.z; s[15]=x3.w;
    }

    if (h == 0) Mg[(size_t)b * 1024 + w * UU + u] = (unsigned char)orig;
}

// ---------------------------------------------------------------------------
// Kernel 4: per-batch backtrack (unchanged, verified).
// ---------------------------------------------------------------------------
__global__ __launch_bounds__(64) void vit_backtrack_kernel(
    const float* __restrict__ chk, const unsigned char* __restrict__ Mg,
    const unsigned char* __restrict__ bpg, int* __restrict__ out)
{
    __shared__ __align__(16) unsigned char bp[(TT - 1) * UU];   // 65504 B

    const int lane = threadIdx.x;
    const int b = blockIdx.x;
    const unsigned char* bb = bpg + (size_t)b * (TT - 1) * UU;

    // stage bp: 4094 int4s
    #pragma unroll 4
    for (int i = 0; i < 64; ++i) {
        const int idx = i * 64 + lane;
        if (idx < 4094)
            ((int4*)bp)[idx] = ((const int4*)bb)[idx];
    }

    // last_tag = argmax_u chk[b][32][u], smallest u on tie
    float fv = (lane < 32) ? chk[((size_t)b * 33 + 32) * UU + lane] : -INFINITY;
    int fi = lane & 31;
    #pragma unroll
    for (int mask = 16; mask >= 1; mask >>= 1) {
        const float ov = __shfl_xor(fv, mask, 64);
        const int oi = __shfl_xor(fi, mask, 64);
        if (ov > fv || (ov == fv && oi < fi)) { fv = ov; fi = oi; }
    }
    int bt = __shfl(fi, 0, 64);

    // boundary walk over Mg (uniform addresses -> broadcast global loads)
    int my_btag = 0;
    #pragma unroll 1
    for (int w = 31; w >= 0; --w) {
        if (lane == w) my_btag = bt;         // tag at t = 64w+63
        bt = Mg[(size_t)b * 1024 + w * 32 + bt];
    }

    __syncthreads();                         // bp staging visible

    if (lane < 32) {
        const int w = lane;
        int tag = my_btag;
        int t = w * 64 + 63;
        int* ob = out + (size_t)b * TT;
        ob[t] = tag;
        #pragma unroll 1
        for (; t >= w * 64 + 1; --t) {
            tag = bp[(t - 1) * UU + tag];
            ob[t - 1] = tag;
        }
    }
}

// ---------------------------------------------------------------------------
extern "C" void kernel_launch(void* const* d_in, const int* in_sizes, int n_in,
                              void* d_out, int out_size, void* d_ws, size_t ws_size,
                              hipStream_t stream)
{
    const float* x     = (const float*)d_in[0];
    const float* K     = (const float*)d_in[1];
    const float* bias  = (const float*)d_in[2];
    const float* chain = (const float*)d_in[3];
    const float* lb    = (const float*)d_in[4];
    const float* rb    = (const float*)d_in[5];
    int* out = (int*)d_out;

    float* pot = (float*)d_ws;                          // 16 MB
    float* chk = pot + (size_t)BB * TT * UU;            // 64*33*32 floats = 264 KB
    unsigned char* Mg  = (unsigned char*)(chk + (size_t)BB * 33 * UU);  // 64 KB
    unsigned char* bpg = Mg + (size_t)BB * 32 * UU;     // 64*2047*32 = 4 MB

    // TIMING PROBE (round 6): potentials launched twice. Idempotent — second
    // launch rewrites identical values. Total delta vs the 529.7 us baseline
    // equals one potentials dispatch, which top-5 profiling cannot show.
    potentials_kernel<<<512, 64, 0, stream>>>(x, K, bias, lb, rb, pot);
    potentials_kernel<<<512, 64, 0, stream>>>(x, K, bias, lb, rb, pot);
    vit_values_kernel<<<BB, 64, 0, stream>>>(pot, chain, chk);
    vit_window_kernel<<<dim3(32, BB), 64, 0, stream>>>(pot, chain, chk, Mg, bpg);
    vit_backtrack_kernel<<<BB, 64, 0, stream>>>(chk, Mg, bpg, out);
}

// Round 7
// 573.182 us; speedup vs baseline: 1.7507x; 1.0982x over previous
//
#include <hip/hip_runtime.h>
#include <hip/hip_bf16.h>
#include <cstdint>

#define BB 64
#define TT 2048
#define FD 256
#define UU 32

// ---------------------------------------------------------------------------
// Kernel 1 v2: pot[b,t,u] = dot(x[b,t,:], K[:,u]) + bias[u] (+ boundaries)
// r6 probe: v1 (512 x 1-wave blocks, 64KB LDS) = 99.8 us — 2 blocks/CU means
// only 2/4 SIMDs busy and FMA-issue serializes with ds_read issue.
// v2: 192-thread blocks (3 waves), each wave owns a 32-row x-tile (3x32KB),
// Kt staged ONCE per block and shared (32KB) -> 128KB LDS, 3 SIMDs busy.
// Per-wave compute identical to v1 (same swizzle, same ascending-f order,
// bit-identical pot). Grid 1366 = ceil(4096/3), tail tiles guarded.
// ---------------------------------------------------------------------------
__global__ __launch_bounds__(192) void potentials_kernel(
    const float* __restrict__ x, const float* __restrict__ K,
    const float* __restrict__ bias, const float* __restrict__ lb,
    const float* __restrict__ rb, float* __restrict__ pot)
{
    __shared__ __align__(16) float lds[32768];   // 128 KB
    const int tid  = threadIdx.x;
    const int w    = tid >> 6;        // wave id 0..2
    const int lane = tid & 63;
    float* xsw = lds + w * 8192;      // this wave's [32 rows][256 f], swizzled
    float* Kt  = lds + 24576;        // shared [32 u][256 f], swizzled

    const int ug = lane & 7;
    const int rg = lane >> 3;

    // Stage K once per block (all 192 threads): K is [f][u] -> Kt[u][f] swizzled.
    for (int j = 0; j < 43; ++j) {
        const int e = j * 192 + tid;
        if (e < 8192) {
            const int f = e >> 5;
            const int u = e & 31;
            Kt[u * 256 + (((f >> 2) ^ (u & 7)) << 2) + (f & 3)] = K[e];
        }
    }

    const int tile = blockIdx.x * 3 + w;
    const bool act = (tile < 4096);
    const int row0 = tile * 32;

    if (act) {
        #pragma unroll 4
        for (int k = 0; k < 32; ++k) {
            const float4 v = *(const float4*)(x + (size_t)(row0 + k) * FD + lane * 4);
            *(float4*)&xsw[k * 256 + ((lane ^ (k & 7)) << 2)] = v;
        }
    }
    __syncthreads();                  // Kt + own xs visible

    if (!act) return;                 // after the only barrier — safe

    float bu[4], lu4[4], ru4[4];
    #pragma unroll
    for (int m = 0; m < 4; ++m) {
        bu[m]  = bias[ug + 8 * m];
        lu4[m] = lb[ug + 8 * m];
        ru4[m] = rb[ug + 8 * m];
    }

    float acc[4][4];
    #pragma unroll
    for (int i = 0; i < 4; ++i)
        #pragma unroll
        for (int m = 0; m < 4; ++m) acc[i][m] = 0.f;

    #pragma unroll 4
    for (int q = 0; q < 64; ++q) {
        float4 xq[4], kq[4];
        #pragma unroll
        for (int i = 0; i < 4; ++i)
            xq[i] = *(const float4*)&xsw[(rg + 8 * i) * 256 + ((q ^ rg) << 2)];
        #pragma unroll
        for (int m = 0; m < 4; ++m)
            kq[m] = *(const float4*)&Kt[(ug + 8 * m) * 256 + ((q ^ ug) << 2)];
        #pragma unroll
        for (int i = 0; i < 4; ++i)
            #pragma unroll
            for (int m = 0; m < 4; ++m) {
                acc[i][m] += xq[i].x * kq[m].x;
                acc[i][m] += xq[i].y * kq[m].y;
                acc[i][m] += xq[i].z * kq[m].z;
                acc[i][m] += xq[i].w * kq[m].w;
            }
    }

    #pragma unroll
    for (int i = 0; i < 4; ++i) {
        const int row = row0 + rg + 8 * i;
        const int t = row & (TT - 1);
        #pragma unroll
        for (int m = 0; m < 4; ++m) {
            pot[(size_t)row * UU + ug + 8 * m] =
                acc[i][m] + bu[m] + (t == 0 ? lu4[m] : 0.f)
                          + (t == TT - 1 ? ru4[m] : 0.f);
        }
    }
}

// ---------------------------------------------------------------------------
// quad_perm [1,0,3,2]: swap adjacent lane pairs via DPP (VALU pipe, no LDS).
// ---------------------------------------------------------------------------
__device__ __forceinline__ float quad_swap(float v) {
    const int i = __float_as_int(v);
    const int r = __builtin_amdgcn_update_dpp(i, i, 0xB1, 0xF, 0xF, true);
    return __int_as_float(r);
}

// ---------------------------------------------------------------------------
// Kernel 2: values-only serial forward — verified v1 (195.8 us).
// Wall time = per-chain serial latency; rounds 1-5 showed LDS roundtrip ~=
// DPP butterfly per step and chain-packing only serializes. Keep v1.
// ---------------------------------------------------------------------------
__global__ __launch_bounds__(64) void vit_values_kernel(
    const float* __restrict__ pot, const float* __restrict__ chain,
    float* __restrict__ chk)
{
    __shared__ __align__(16) float mbuf[32];

    const int lane = threadIdx.x;
    const int u = lane >> 1;
    const int q = lane & 1;
    const int qb = 16 * q;
    const int b = blockIdx.x;
    const float* pb = pot + (size_t)b * TT * UU;

    float cc[16];
    #pragma unroll
    for (int i = 0; i < 16; ++i) cc[i] = chain[(qb + i) * UU + u];

    float s[16];
    {
        const float4* s0 = (const float4*)(pb + qb);
        #pragma unroll
        for (int k = 0; k < 4; ++k) {
            const float4 v = s0[k];
            s[4*k+0] = v.x; s[4*k+1] = v.y; s[4*k+2] = v.z; s[4*k+3] = v.w;
        }
    }

    auto step = [&](float potv, int t) {
        float a[16];
        #pragma unroll
        for (int i = 0; i < 16; ++i) a[i] = s[i] + cc[i];
        float m8[8];
        #pragma unroll
        for (int i = 0; i < 8; ++i) m8[i] = fmaxf(a[2*i], a[2*i+1]);
        float m4[4];
        #pragma unroll
        for (int i = 0; i < 4; ++i) m4[i] = fmaxf(m8[2*i], m8[2*i+1]);
        const float pm = fmaxf(fmaxf(m4[0], m4[1]), fmaxf(m4[2], m4[3]));
        const float om = quad_swap(pm);          // other half's partial max
        const float mm = fmaxf(pm, om) + potv;   // exact max, single rounding

        mbuf[u] = mm;                            // both q-lanes write same value

        if ((t & 63) == 63)
            chk[((size_t)b * 33 + ((t >> 6) + 1)) * UU + u] = mm;

        const float4 x0 = *(const float4*)&mbuf[qb + 0];
        const float4 x1 = *(const float4*)&mbuf[qb + 4];
        const float4 x2 = *(const float4*)&mbuf[qb + 8];
        const float4 x3 = *(const float4*)&mbuf[qb + 12];
        s[0]=x0.x;  s[1]=x0.y;  s[2]=x0.z;  s[3]=x0.w;
        s[4]=x1.x;  s[5]=x1.y;  s[6]=x1.z;  s[7]=x1.w;
        s[8]=x2.x;  s[9]=x2.y;  s[10]=x2.z; s[11]=x2.w;
        s[12]=x3.x; s[13]=x3.y; s[14]=x3.z; s[15]=x3.w;
    };

    float pr[8], pn[8];
    #pragma unroll
    for (int j = 0; j < 8; ++j) pr[j] = pb[(1 + j) * UU + u];

    #pragma unroll 1
    for (int g = 0; g < 255; ++g) {
        #pragma unroll
        for (int j = 0; j < 8; ++j) {
            int tp = 9 + 8 * g + j;
            if (tp > TT - 1) tp = TT - 1;
            pn[j] = pb[tp * UU + u];
        }
        const int t0 = 1 + 8 * g;
        #pragma unroll
        for (int j = 0; j < 8; ++j)
            step(pr[j], t0 + j);
        #pragma unroll
        for (int j = 0; j < 8; ++j) pr[j] = pn[j];
    }
    // tail: t = 2041..2047 (includes final checkpoint wck = 32 at t = 2047)
    #pragma unroll
    for (int j = 0; j < 7; ++j)
        step(pr[j], 2041 + j);
}

// ---------------------------------------------------------------------------
// Kernel 3: parallel window recompute (unchanged, verified).
// NOTE (round 7): launched TWICE as a timing probe — idempotent.
// ---------------------------------------------------------------------------
__global__ __launch_bounds__(64) void vit_window_kernel(
    const float* __restrict__ pot, const float* __restrict__ chain,
    const float* __restrict__ chk, unsigned char* __restrict__ Mg,
    unsigned char* __restrict__ bpg)
{
    __shared__ float potL[64 * 32];   // 8 KB: pot rows 64w .. 64w+63
    __shared__ float mbuf[32];

    const int lane = threadIdx.x;
    const int u = lane & 31;
    const int h = lane >> 5;
    const int hbase = 16 * h;
    const int w = blockIdx.x;
    const int b = blockIdx.y;
    const float* pb = pot + (size_t)b * TT * UU;
    const int r0 = 64 * w;

    {
        const float4* src = (const float4*)(pb + (size_t)r0 * UU);
        float4* dst = (float4*)potL;
        #pragma unroll
        for (int k = 0; k < 8; ++k) dst[lane + 64 * k] = src[lane + 64 * k];
    }
    __syncthreads();

    float cc[16];
    #pragma unroll
    for (int i = 0; i < 16; ++i) cc[i] = chain[(hbase + i) * UU + u];

    float s[16];
    if (w == 0) {
        #pragma unroll
        for (int i = 0; i < 16; ++i) s[i] = potL[hbase + i];          // state t=0
    } else {
        #pragma unroll
        for (int i = 0; i < 16; ++i) s[i] = chk[((size_t)b * 33 + w) * UU + hbase + i];
    }

    int orig = u;
    unsigned char* bb = bpg + (size_t)b * (TT - 1) * UU;

    const int tl0 = (w == 0) ? 1 : 0;
    #pragma unroll 1
    for (int tl = tl0; tl < 64; ++tl) {
        const int t = r0 + tl;
        const float potv = potL[tl * UU + u];

        float a[16];
        #pragma unroll
        for (int i = 0; i < 16; ++i) a[i] = s[i] + cc[i];

        // first-occurrence argmax: pairwise tree, right wins only if strictly >
        float v8[8]; int i8[8];
        #pragma unroll
        for (int i = 0; i < 8; ++i) {
            const bool c = a[2*i+1] > a[2*i];
            v8[i] = c ? a[2*i+1] : a[2*i];
            i8[i] = c ? (2*i+1) : (2*i);
        }
        float v4[4]; int i4[4];
        #pragma unroll
        for (int i = 0; i < 4; ++i) {
            const bool c = v8[2*i+1] > v8[2*i];
            v4[i] = c ? v8[2*i+1] : v8[2*i];
            i4[i] = c ? i8[2*i+1] : i8[2*i];
        }
        float v2[2]; int i2[2];
        #pragma unroll
        for (int i = 0; i < 2; ++i) {
            const bool c = v4[2*i+1] > v4[2*i];
            v2[i] = c ? v4[2*i+1] : v4[2*i];
            i2[i] = c ? i4[2*i+1] : i4[2*i];
        }
        const bool cf = v2[1] > v2[0];
        const float pv = cf ? v2[1] : v2[0];
        const int pidx = hbase + (cf ? i2[1] : i2[0]);

        const float opv = __shfl_xor(pv, 32, 64);
        const int   opi = __shfl_xor(pidx, 32, 64);
        const bool take = h ? (opv >= pv) : (opv > pv);   // tie -> lower half
        const int  mv   = take ? opi : pidx;
        const float mm  = fmaxf(pv, opv) + potv;

        if (h == 0) bb[(size_t)(t - 1) * UU + u] = (unsigned char)mv;
        orig = __shfl(orig, mv, 64);

        mbuf[u] = mm;
        const float4 x0 = *(const float4*)&mbuf[hbase + 0];
        const float4 x1 = *(const float4*)&mbuf[hbase + 4];
        const float4 x2 = *(const float4*)&mbuf[hbase + 8];
        const float4 x3 = *(const float4*)&mbuf[hbase + 12];
        s[0]=x0.x; s[1]=x0.y; s[2]=x0.z;  s[3]=x0.w;
        s[4]=x1.x; s[5]=x1.y; s[6]=x1.z;  s[7]=x1.w;
        s[8]=x2.x; s[9]=x2.y; s[10]=x2.z; s[11]=x2.w;
        s[12]=x3.x; s[13]=x3.y; s[14]=x3.z; s[15]=x3.w;
    }

    if (h == 0) Mg[(size_t)b * 1024 + w * UU + u] = (unsigned char)orig;
}

// ---------------------------------------------------------------------------
// Kernel 4: per-batch backtrack (unchanged, verified).
// NOTE (round 7): launched TWICE as a timing probe — idempotent.
// ---------------------------------------------------------------------------
__global__ __launch_bounds__(64) void vit_backtrack_kernel(
    const float* __restrict__ chk, const unsigned char* __restrict__ Mg,
    const unsigned char* __restrict__ bpg, int* __restrict__ out)
{
    __shared__ __align__(16) unsigned char bp[(TT - 1) * UU];   // 65504 B

    const int lane = threadIdx.x;
    const int b = blockIdx.x;
    const unsigned char* bb = bpg + (size_t)b * (TT - 1) * UU;

    // stage bp: 4094 int4s
    #pragma unroll 4
    for (int i = 0; i < 64; ++i) {
        const int idx = i * 64 + lane;
        if (idx < 4094)
            ((int4*)bp)[idx] = ((const int4*)bb)[idx];
    }

    // last_tag = argmax_u chk[b][32][u], smallest u on tie
    float fv = (lane < 32) ? chk[((size_t)b * 33 + 32) * UU + lane] : -INFINITY;
    int fi = lane & 31;
    #pragma unroll
    for (int mask = 16; mask >= 1; mask >>= 1) {
        const float ov = __shfl_xor(fv, mask, 64);
        const int oi = __shfl_xor(fi, mask, 64);
        if (ov > fv || (ov == fv && oi < fi)) { fv = ov; fi = oi; }
    }
    int bt = __shfl(fi, 0, 64);

    // boundary walk over Mg (uniform addresses -> broadcast global loads)
    int my_btag = 0;
    #pragma unroll 1
    for (int w = 31; w >= 0; --w) {
        if (lane == w) my_btag = bt;         // tag at t = 64w+63
        bt = Mg[(size_t)b * 1024 + w * 32 + bt];
    }

    __syncthreads();                         // bp staging visible

    if (lane < 32) {
        const int w = lane;
        int tag = my_btag;
        int t = w * 64 + 63;
        int* ob = out + (size_t)b * TT;
        ob[t] = tag;
        #pragma unroll 1
        for (; t >= w * 64 + 1; --t) {
            tag = bp[(t - 1) * UU + tag];
            ob[t - 1] = tag;
        }
    }
}

// ---------------------------------------------------------------------------
extern "C" void kernel_launch(void* const* d_in, const int* in_sizes, int n_in,
                              void* d_out, int out_size, void* d_ws, size_t ws_size,
                              hipStream_t stream)
{
    const float* x     = (const float*)d_in[0];
    const float* K     = (const float*)d_in[1];
    const float* bias  = (const float*)d_in[2];
    const float* chain = (const float*)d_in[3];
    const float* lb    = (const float*)d_in[4];
    const float* rb    = (const float*)d_in[5];
    int* out = (int*)d_out;

    float* pot = (float*)d_ws;                          // 16 MB
    float* chk = pot + (size_t)BB * TT * UU;            // 64*33*32 floats = 264 KB
    unsigned char* Mg  = (unsigned char*)(chk + (size_t)BB * 33 * UU);  // 64 KB
    unsigned char* bpg = Mg + (size_t)BB * 32 * UU;     // 64*2047*32 = 4 MB

    potentials_kernel<<<1366, 192, 0, stream>>>(x, K, bias, lb, rb, pot);
    vit_values_kernel<<<BB, 64, 0, stream>>>(pot, chain, chk);
    // TIMING PROBE (round 7): window + backtrack launched twice (idempotent).
    // new_total - 529.7 = (P_new - 99.8) + (W + Bk) + launch gaps.
    vit_window_kernel<<<dim3(32, BB), 64, 0, stream>>>(pot, chain, chk, Mg, bpg);
    vit_window_kernel<<<dim3(32, BB), 64, 0, stream>>>(pot, chain, chk, Mg, bpg);
    vit_backtrack_kernel<<<BB, 64, 0, stream>>>(chk, Mg, bpg, out);
    vit_backtrack_kernel<<<BB, 64, 0, stream>>>(chk, Mg, bpg, out);
}

// Round 8
// 480.722 us; speedup vs baseline: 2.0874x; 1.1923x over previous
//
#include <hip/hip_runtime.h>
#include <hip/hip_bf16.h>
#include <cstdint>

#define BB 64
#define TT 2048
#define FD 256
#define UU 32

// ---------------------------------------------------------------------------
// Kernel 1 v3: pot[b,t,u] = dot(x[b,t,:], K[:,u]) + bias[u] (+ boundaries)
// r6 probe: v1 (both operands via LDS) = 99.8 us. Model: one LDS pipe/CU
// serializes 512 ds_read_b128 per tile (~6.1k cyc) and 64KB LDS capped
// occupancy at 2 waves/CU. v3 splits the pipes: x comes straight from
// GLOBAL (no transpose needed — 8 lanes/address broadcast, 64B lines reused
// across 4 consecutive q -> one-pass 128MB HBM), only K (which needs the
// [f][u]->[u][f] transpose) stays in LDS (32KB, v1's verified swizzle).
// LDS instr/tile halves; 32KB LDS -> 4 blocks/CU; no in-loop barrier.
// Value-identical to v1: the global float4 x[row][4q..4q+3] is exactly what
// the xs slot held; FMA order (ascending f) and epilogue unchanged.
// ---------------------------------------------------------------------------
__global__ __launch_bounds__(64) void potentials_kernel(
    const float* __restrict__ x, const float* __restrict__ K,
    const float* __restrict__ bias, const float* __restrict__ lb,
    const float* __restrict__ rb, float* __restrict__ pot)
{
    __shared__ __align__(16) float Kt[8192];   // 32 KB: [32 u][256 f], swizzled

    const int lane = threadIdx.x;
    const int ug = lane & 7;
    const int rg = lane >> 3;

    // Stage K (once per block): K is [f][u] row-major -> Kt[u][f] swizzled.
    for (int j = 0; j < 128; ++j) {
        const int e = j * 64 + lane;
        const int f = e >> 5;
        const int u = e & 31;
        Kt[u * 256 + (((f >> 2) ^ (u & 7)) << 2) + (f & 3)] = K[e];
    }
    __syncthreads();                  // Kt read-only afterwards — only barrier

    float bu[4], lu4[4], ru4[4];
    #pragma unroll
    for (int m = 0; m < 4; ++m) {
        bu[m]  = bias[ug + 8 * m];
        lu4[m] = lb[ug + 8 * m];
        ru4[m] = rb[ug + 8 * m];
    }

    const int tiles = (BB * TT) / 32;     // 4096; grid 1024 -> 4 tiles/block
    for (int tile = blockIdx.x; tile < tiles; tile += gridDim.x) {
        const int row0 = tile * 32;

        float acc[4][4];
        #pragma unroll
        for (int i = 0; i < 4; ++i)
            #pragma unroll
            for (int m = 0; m < 4; ++m) acc[i][m] = 0.f;

        #pragma unroll 4
        for (int q = 0; q < 64; ++q) {
            float4 xq[4], kq[4];
            #pragma unroll
            for (int i = 0; i < 4; ++i)
                xq[i] = *(const float4*)(x + (size_t)(row0 + rg + 8 * i) * FD + q * 4);
            #pragma unroll
            for (int m = 0; m < 4; ++m)
                kq[m] = *(const float4*)&Kt[(ug + 8 * m) * 256 + ((q ^ ug) << 2)];
            #pragma unroll
            for (int i = 0; i < 4; ++i)
                #pragma unroll
                for (int m = 0; m < 4; ++m) {
                    acc[i][m] += xq[i].x * kq[m].x;
                    acc[i][m] += xq[i].y * kq[m].y;
                    acc[i][m] += xq[i].z * kq[m].z;
                    acc[i][m] += xq[i].w * kq[m].w;
                }
        }

        #pragma unroll
        for (int i = 0; i < 4; ++i) {
            const int row = row0 + rg + 8 * i;
            const int t = row & (TT - 1);
            #pragma unroll
            for (int m = 0; m < 4; ++m) {
                pot[(size_t)row * UU + ug + 8 * m] =
                    acc[i][m] + bu[m] + (t == 0 ? lu4[m] : 0.f)
                              + (t == TT - 1 ? ru4[m] : 0.f);
            }
        }
    }
}

// ---------------------------------------------------------------------------
// quad_perm [1,0,3,2]: swap adjacent lane pairs via DPP (VALU pipe, no LDS).
// ---------------------------------------------------------------------------
__device__ __forceinline__ float quad_swap(float v) {
    const int i = __float_as_int(v);
    const int r = __builtin_amdgcn_update_dpp(i, i, 0xB1, 0xF, 0xF, true);
    return __int_as_float(r);
}

// ---------------------------------------------------------------------------
// Kernel 2: values-only serial forward — verified v1 (195.8 us).
// Wall time = per-chain serial latency; rounds 1-5 showed LDS roundtrip ~=
// DPP butterfly per step and chain-packing only serializes. Keep v1.
// ---------------------------------------------------------------------------
__global__ __launch_bounds__(64) void vit_values_kernel(
    const float* __restrict__ pot, const float* __restrict__ chain,
    float* __restrict__ chk)
{
    __shared__ __align__(16) float mbuf[32];

    const int lane = threadIdx.x;
    const int u = lane >> 1;
    const int q = lane & 1;
    const int qb = 16 * q;
    const int b = blockIdx.x;
    const float* pb = pot + (size_t)b * TT * UU;

    float cc[16];
    #pragma unroll
    for (int i = 0; i < 16; ++i) cc[i] = chain[(qb + i) * UU + u];

    float s[16];
    {
        const float4* s0 = (const float4*)(pb + qb);
        #pragma unroll
        for (int k = 0; k < 4; ++k) {
            const float4 v = s0[k];
            s[4*k+0] = v.x; s[4*k+1] = v.y; s[4*k+2] = v.z; s[4*k+3] = v.w;
        }
    }

    auto step = [&](float potv, int t) {
        float a[16];
        #pragma unroll
        for (int i = 0; i < 16; ++i) a[i] = s[i] + cc[i];
        float m8[8];
        #pragma unroll
        for (int i = 0; i < 8; ++i) m8[i] = fmaxf(a[2*i], a[2*i+1]);
        float m4[4];
        #pragma unroll
        for (int i = 0; i < 4; ++i) m4[i] = fmaxf(m8[2*i], m8[2*i+1]);
        const float pm = fmaxf(fmaxf(m4[0], m4[1]), fmaxf(m4[2], m4[3]));
        const float om = quad_swap(pm);          // other half's partial max
        const float mm = fmaxf(pm, om) + potv;   // exact max, single rounding

        mbuf[u] = mm;                            // both q-lanes write same value

        if ((t & 63) == 63)
            chk[((size_t)b * 33 + ((t >> 6) + 1)) * UU + u] = mm;

        const float4 x0 = *(const float4*)&mbuf[qb + 0];
        const float4 x1 = *(const float4*)&mbuf[qb + 4];
        const float4 x2 = *(const float4*)&mbuf[qb + 8];
        const float4 x3 = *(const float4*)&mbuf[qb + 12];
        s[0]=x0.x;  s[1]=x0.y;  s[2]=x0.z;  s[3]=x0.w;
        s[4]=x1.x;  s[5]=x1.y;  s[6]=x1.z;  s[7]=x1.w;
        s[8]=x2.x;  s[9]=x2.y;  s[10]=x2.z; s[11]=x2.w;
        s[12]=x3.x; s[13]=x3.y; s[14]=x3.z; s[15]=x3.w;
    };

    float pr[8], pn[8];
    #pragma unroll
    for (int j = 0; j < 8; ++j) pr[j] = pb[(1 + j) * UU + u];

    #pragma unroll 1
    for (int g = 0; g < 255; ++g) {
        #pragma unroll
        for (int j = 0; j < 8; ++j) {
            int tp = 9 + 8 * g + j;
            if (tp > TT - 1) tp = TT - 1;
            pn[j] = pb[tp * UU + u];
        }
        const int t0 = 1 + 8 * g;
        #pragma unroll
        for (int j = 0; j < 8; ++j)
            step(pr[j], t0 + j);
        #pragma unroll
        for (int j = 0; j < 8; ++j) pr[j] = pn[j];
    }
    // tail: t = 2041..2047 (includes final checkpoint wck = 32 at t = 2047)
    #pragma unroll
    for (int j = 0; j < 7; ++j)
        step(pr[j], 2041 + j);
}

// ---------------------------------------------------------------------------
// Kernel 3: parallel window recompute (unchanged, verified).
// ---------------------------------------------------------------------------
__global__ __launch_bounds__(64) void vit_window_kernel(
    const float* __restrict__ pot, const float* __restrict__ chain,
    const float* __restrict__ chk, unsigned char* __restrict__ Mg,
    unsigned char* __restrict__ bpg)
{
    __shared__ float potL[64 * 32];   // 8 KB: pot rows 64w .. 64w+63
    __shared__ float mbuf[32];

    const int lane = threadIdx.x;
    const int u = lane & 31;
    const int h = lane >> 5;
    const int hbase = 16 * h;
    const int w = blockIdx.x;
    const int b = blockIdx.y;
    const float* pb = pot + (size_t)b * TT * UU;
    const int r0 = 64 * w;

    {
        const float4* src = (const float4*)(pb + (size_t)r0 * UU);
        float4* dst = (float4*)potL;
        #pragma unroll
        for (int k = 0; k < 8; ++k) dst[lane + 64 * k] = src[lane + 64 * k];
    }
    __syncthreads();

    float cc[16];
    #pragma unroll
    for (int i = 0; i < 16; ++i) cc[i] = chain[(hbase + i) * UU + u];

    float s[16];
    if (w == 0) {
        #pragma unroll
        for (int i = 0; i < 16; ++i) s[i] = potL[hbase + i];          // state t=0
    } else {
        #pragma unroll
        for (int i = 0; i < 16; ++i) s[i] = chk[((size_t)b * 33 + w) * UU + hbase + i];
    }

    int orig = u;
    unsigned char* bb = bpg + (size_t)b * (TT - 1) * UU;

    const int tl0 = (w == 0) ? 1 : 0;
    #pragma unroll 1
    for (int tl = tl0; tl < 64; ++tl) {
        const int t = r0 + tl;
        const float potv = potL[tl * UU + u];

        float a[16];
        #pragma unroll
        for (int i = 0; i < 16; ++i) a[i] = s[i] + cc[i];

        // first-occurrence argmax: pairwise tree, right wins only if strictly >
        float v8[8]; int i8[8];
        #pragma unroll
        for (int i = 0; i < 8; ++i) {
            const bool c = a[2*i+1] > a[2*i];
            v8[i] = c ? a[2*i+1] : a[2*i];
            i8[i] = c ? (2*i+1) : (2*i);
        }
        float v4[4]; int i4[4];
        #pragma unroll
        for (int i = 0; i < 4; ++i) {
            const bool c = v8[2*i+1] > v8[2*i];
            v4[i] = c ? v8[2*i+1] : v8[2*i];
            i4[i] = c ? i8[2*i+1] : i8[2*i];
        }
        float v2[2]; int i2[2];
        #pragma unroll
        for (int i = 0; i < 2; ++i) {
            const bool c = v4[2*i+1] > v4[2*i];
            v2[i] = c ? v4[2*i+1] : v4[2*i];
            i2[i] = c ? i4[2*i+1] : i4[2*i];
        }
        const bool cf = v2[1] > v2[0];
        const float pv = cf ? v2[1] : v2[0];
        const int pidx = hbase + (cf ? i2[1] : i2[0]);

        const float opv = __shfl_xor(pv, 32, 64);
        const int   opi = __shfl_xor(pidx, 32, 64);
        const bool take = h ? (opv >= pv) : (opv > pv);   // tie -> lower half
        const int  mv   = take ? opi : pidx;
        const float mm  = fmaxf(pv, opv) + potv;

        if (h == 0) bb[(size_t)(t - 1) * UU + u] = (unsigned char)mv;
        orig = __shfl(orig, mv, 64);

        mbuf[u] = mm;
        const float4 x0 = *(const float4*)&mbuf[hbase + 0];
        const float4 x1 = *(const float4*)&mbuf[hbase + 4];
        const float4 x2 = *(const float4*)&mbuf[hbase + 8];
        const float4 x3 = *(const float4*)&mbuf[hbase + 12];
        s[0]=x0.x; s[1]=x0.y; s[2]=x0.z;  s[3]=x0.w;
        s[4]=x1.x; s[5]=x1.y; s[6]=x1.z;  s[7]=x1.w;
        s[8]=x2.x; s[9]=x2.y; s[10]=x2.z; s[11]=x2.w;
        s[12]=x3.x; s[13]=x3.y; s[14]=x3.z; s[15]=x3.w;
    }

    if (h == 0) Mg[(size_t)b * 1024 + w * UU + u] = (unsigned char)orig;
}

// ---------------------------------------------------------------------------
// Kernel 4: per-batch backtrack (unchanged, verified).
// ---------------------------------------------------------------------------
__global__ __launch_bounds__(64) void vit_backtrack_kernel(
    const float* __restrict__ chk, const unsigned char* __restrict__ Mg,
    const unsigned char* __restrict__ bpg, int* __restrict__ out)
{
    __shared__ __align__(16) unsigned char bp[(TT - 1) * UU];   // 65504 B

    const int lane = threadIdx.x;
    const int b = blockIdx.x;
    const unsigned char* bb = bpg + (size_t)b * (TT - 1) * UU;

    // stage bp: 4094 int4s
    #pragma unroll 4
    for (int i = 0; i < 64; ++i) {
        const int idx = i * 64 + lane;
        if (idx < 4094)
            ((int4*)bp)[idx] = ((const int4*)bb)[idx];
    }

    // last_tag = argmax_u chk[b][32][u], smallest u on tie
    float fv = (lane < 32) ? chk[((size_t)b * 33 + 32) * UU + lane] : -INFINITY;
    int fi = lane & 31;
    #pragma unroll
    for (int mask = 16; mask >= 1; mask >>= 1) {
        const float ov = __shfl_xor(fv, mask, 64);
        const int oi = __shfl_xor(fi, mask, 64);
        if (ov > fv || (ov == fv && oi < fi)) { fv = ov; fi = oi; }
    }
    int bt = __shfl(fi, 0, 64);

    // boundary walk over Mg (uniform addresses -> broadcast global loads)
    int my_btag = 0;
    #pragma unroll 1
    for (int w = 31; w >= 0; --w) {
        if (lane == w) my_btag = bt;         // tag at t = 64w+63
        bt = Mg[(size_t)b * 1024 + w * 32 + bt];
    }

    __syncthreads();                         // bp staging visible

    if (lane < 32) {
        const int w = lane;
        int tag = my_btag;
        int t = w * 64 + 63;
        int* ob = out + (size_t)b * TT;
        ob[t] = tag;
        #pragma unroll 1
        for (; t >= w * 64 + 1; --t) {
            tag = bp[(t - 1) * UU + tag];
            ob[t - 1] = tag;
        }
    }
}

// ---------------------------------------------------------------------------
extern "C" void kernel_launch(void* const* d_in, const int* in_sizes, int n_in,
                              void* d_out, int out_size, void* d_ws, size_t ws_size,
                              hipStream_t stream)
{
    const float* x     = (const float*)d_in[0];
    const float* K     = (const float*)d_in[1];
    const float* bias  = (const float*)d_in[2];
    const float* chain = (const float*)d_in[3];
    const float* lb    = (const float*)d_in[4];
    const float* rb    = (const float*)d_in[5];
    int* out = (int*)d_out;

    float* pot = (float*)d_ws;                          // 16 MB
    float* chk = pot + (size_t)BB * TT * UU;            // 64*33*32 floats = 264 KB
    unsigned char* Mg  = (unsigned char*)(chk + (size_t)BB * 33 * UU);  // 64 KB
    unsigned char* bpg = Mg + (size_t)BB * 32 * UU;     // 64*2047*32 = 4 MB

    // Clean config (round 8): v3 potentials, single launches everywhere.
    // P_v3 = total - 429.9 (values 195.8 + W/Bk/OH 234.1, both invariant).
    potentials_kernel<<<1024, 64, 0, stream>>>(x, K, bias, lb, rb, pot);
    vit_values_kernel<<<BB, 64, 0, stream>>>(pot, chain, chk);
    vit_window_kernel<<<dim3(32, BB), 64, 0, stream>>>(pot, chain, chk, Mg, bpg);
    vit_backtrack_kernel<<<BB, 64, 0, stream>>>(chk, Mg, bpg, out);
}